// Round 1
// baseline (685.465 us; speedup 1.0000x reference)
//
#include <hip/hip_runtime.h>
#include <hip/hip_bf16.h>

#define B_ 32
#define N_ 1024
#define D_ 512
#define LN_EPS 1e-5f

using bf16 = __bf16;
using bf16x8 = __attribute__((ext_vector_type(8))) __bf16;
using floatx4 = __attribute__((ext_vector_type(4))) float;

// ---------------- deg / dis ----------------
__global__ __launch_bounds__(256) void k_deg(const float* __restrict__ A,
                                             float* __restrict__ dis) {
  int idx = blockIdx.x * 256 + threadIdx.x;      // b*N + j
  int b = idx >> 10, j = idx & 1023;
  const float* p = A + (size_t)b * N_ * N_ + j;
  float s = 0.f;
  #pragma unroll 4
  for (int i = 0; i < N_; ++i) s += p[(size_t)i * N_];
  dis[idx] = s > 0.f ? rsqrtf(s) : 0.f;
}

// ------------- build Abf (straight cast) + Anbf (transpose*dis*dis) -------------
__global__ __launch_bounds__(256) void k_build(const float* __restrict__ A,
                                               const float* __restrict__ dis,
                                               bf16* __restrict__ Abf,
                                               bf16* __restrict__ Anbf) {
  __shared__ float tile[64][65];
  int b = blockIdx.z;
  int i0 = blockIdx.x * 64;   // i range (cols of A read, rows of An)
  int j0 = blockIdx.y * 64;   // j range (rows of A read)
  int t = threadIdx.x;
  const float* Ab = A + (size_t)b * N_ * N_;
  bf16* Abfb = Abf + (size_t)b * N_ * N_;
  bf16* Anb = Anbf + (size_t)b * N_ * N_;
  #pragma unroll
  for (int cc = 0; cc < 4; ++cc) {
    int chunk = cc * 256 + t;       // 0..1023
    int r = chunk >> 4;             // 0..63 (row j offset)
    int c4 = (chunk & 15) << 2;     // 0..60
    const float4 v = *(const float4*)(Ab + (size_t)(j0 + r) * N_ + i0 + c4);
    tile[r][c4 + 0] = v.x; tile[r][c4 + 1] = v.y;
    tile[r][c4 + 2] = v.z; tile[r][c4 + 3] = v.w;
    bf16* dst = Abfb + (size_t)(j0 + r) * N_ + i0 + c4;
    dst[0] = (bf16)v.x; dst[1] = (bf16)v.y; dst[2] = (bf16)v.z; dst[3] = (bf16)v.w;
  }
  __syncthreads();
  const float* disb = dis + b * N_;
  #pragma unroll
  for (int cc = 0; cc < 4; ++cc) {
    int chunk = cc * 256 + t;
    int ii = chunk >> 4;            // 0..63 (out row offset)
    int jj4 = (chunk & 15) << 2;
    float di = disb[i0 + ii];
    bf16* dst = Anb + (size_t)(i0 + ii) * N_ + j0 + jj4;
    #pragma unroll
    for (int e = 0; e < 4; ++e) {
      float v = tile[jj4 + e][ii] * di * disb[j0 + jj4 + e];
      dst[e] = (bf16)v;
    }
  }
}

// ---------------- cast weights to bf16 ----------------
__global__ __launch_bounds__(256) void k_castw(const float* __restrict__ W1,
                                               const float* __restrict__ W2,
                                               bf16* __restrict__ W1bf,
                                               bf16* __restrict__ W2bf) {
  int idx = blockIdx.x * 256 + threadIdx.x;
  if (idx < N_ * D_) W1bf[idx] = (bf16)W1[idx];
  int i2 = idx - N_ * D_;
  if (i2 >= 0 && i2 < D_ * D_) W2bf[i2] = (bf16)W2[i2];
}

// ---------------- MFMA GEMM: C[M,N] = A[M,K] @ B[K,N] (+bias)(relu), bf16 out ----
template <bool BIAS, bool RELU>
__global__ __launch_bounds__(256) void k_gemm(
    const bf16* __restrict__ Abase, size_t strideA,
    const bf16* __restrict__ Bbase, size_t strideB,
    bf16* __restrict__ Cbase, size_t strideC,
    const float* __restrict__ bias, int Nn, int K) {
  constexpr int LDA = 56;   // bf16 units, 112B rows -> 16B aligned, 2-way max
  constexpr int LDB = 130;  // natural [k][n]; quad row offset 8*260B -> distinct banks
  __shared__ bf16 sA[128 * LDA];
  __shared__ bf16 sB[32 * LDB];
  int b = blockIdx.z;
  int n0 = blockIdx.x * 128;
  int m0 = blockIdx.y * 128;
  const bf16* A = Abase + (size_t)b * strideA;
  const bf16* Bm = Bbase + (size_t)b * strideB;
  int t = threadIdx.x;
  int lane = t & 63, wid = t >> 6;
  int wm = (wid >> 1) * 64, wn = (wid & 1) * 64;
  int l16 = lane & 15, q = lane >> 4;

  floatx4 acc[4][4];
  #pragma unroll
  for (int i = 0; i < 4; ++i)
    #pragma unroll
    for (int j = 0; j < 4; ++j) acc[i][j] = (floatx4){0.f, 0.f, 0.f, 0.f};

  for (int kt = 0; kt < K; kt += 32) {
    // stage A tile: 128 rows x 32 cols, [m][k] layout
    #pragma unroll
    for (int cc = 0; cc < 2; ++cc) {
      int chunk = t * 2 + cc;          // 0..511
      int r = chunk >> 2;              // 0..127
      int c8 = (chunk & 3) << 3;       // 0,8,16,24
      uint4 v = *(const uint4*)(A + (size_t)(m0 + r) * K + kt + c8);
      *(uint4*)(&sA[r * LDA + c8]) = v;
    }
    // stage B tile: 32 rows x 128 cols, natural [k][n] layout
    #pragma unroll
    for (int cc = 0; cc < 2; ++cc) {
      int chunk = t * 2 + cc;
      int r = chunk >> 4;              // 0..31
      int c8 = (chunk & 15) << 3;      // 0..120
      uint4 v = *(const uint4*)(Bm + (size_t)(kt + r) * Nn + n0 + c8);
      uint vv[4] = {v.x, v.y, v.z, v.w};
      #pragma unroll
      for (int e = 0; e < 4; ++e)
        *(uint*)(&sB[r * LDB + c8 + 2 * e]) = vv[e];
    }
    __syncthreads();

    bf16x8 af[4];
    #pragma unroll
    for (int mt = 0; mt < 4; ++mt)
      af[mt] = *(const bf16x8*)(&sA[(wm + mt * 16 + l16) * LDA + q * 8]);
    bf16x8 bfg[4];
    #pragma unroll
    for (int nt = 0; nt < 4; ++nt) {
      bf16x8 bv;
      #pragma unroll
      for (int j = 0; j < 8; ++j)
        bv[j] = sB[(q * 8 + j) * LDB + wn + nt * 16 + l16];
      bfg[nt] = bv;
    }
    #pragma unroll
    for (int mt = 0; mt < 4; ++mt)
      #pragma unroll
      for (int nt = 0; nt < 4; ++nt)
        acc[mt][nt] = __builtin_amdgcn_mfma_f32_16x16x32_bf16(
            af[mt], bfg[nt], acc[mt][nt], 0, 0, 0);
    __syncthreads();
  }

  bf16* C = Cbase + (size_t)b * strideC;
  #pragma unroll
  for (int mt = 0; mt < 4; ++mt)
    #pragma unroll
    for (int nt = 0; nt < 4; ++nt)
      #pragma unroll
      for (int r = 0; r < 4; ++r) {
        int row = m0 + wm + mt * 16 + q * 4 + r;
        int col = n0 + wn + nt * 16 + l16;
        float v = acc[mt][nt][r];
        if (BIAS) v += bias[col];
        if (RELU) v = v > 0.f ? v : 0.f;
        C[(size_t)row * Nn + col] = (bf16)v;
      }
}

// ---------------- LayerNorm over D + mean-pool over N (accumulate) ----------------
__global__ __launch_bounds__(256) void k_lnpool(const bf16* __restrict__ H2,
                                                const float* __restrict__ g,
                                                const float* __restrict__ be,
                                                float* __restrict__ zp_accum) {
  int b = blockIdx.y;
  int r0 = blockIdx.x * 64;
  int t = threadIdx.x, lane = t & 63, w = t >> 6;
  float ge[8], bee[8];
  #pragma unroll
  for (int e = 0; e < 8; ++e) { ge[e] = g[lane * 8 + e]; bee[e] = be[lane * 8 + e]; }
  float acc[8] = {0, 0, 0, 0, 0, 0, 0, 0};
  for (int rr = 0; rr < 16; ++rr) {
    int row = r0 + w * 16 + rr;
    const bf16* p = H2 + ((size_t)b * N_ + row) * D_ + lane * 8;
    bf16x8 hv = *(const bf16x8*)p;
    float x[8];
    float s = 0.f;
    #pragma unroll
    for (int e = 0; e < 8; ++e) { x[e] = (float)hv[e]; s += x[e]; }
    #pragma unroll
    for (int off = 32; off; off >>= 1) s += __shfl_xor(s, off);
    float mu = s * (1.f / 512.f);
    float ss = 0.f;
    #pragma unroll
    for (int e = 0; e < 8; ++e) { float d = x[e] - mu; ss += d * d; }
    #pragma unroll
    for (int off = 32; off; off >>= 1) ss += __shfl_xor(ss, off);
    float rs = rsqrtf(ss * (1.f / 512.f) + LN_EPS);
    #pragma unroll
    for (int e = 0; e < 8; ++e) acc[e] += (x[e] - mu) * rs * ge[e] + bee[e];
  }
  __shared__ float part[4][512];
  #pragma unroll
  for (int e = 0; e < 8; ++e) part[w][lane * 8 + e] = acc[e];
  __syncthreads();
  #pragma unroll
  for (int k = 0; k < 2; ++k) {
    int d = t + k * 256;
    float s4 = part[0][d] + part[1][d] + part[2][d] + part[3][d];
    atomicAdd(&zp_accum[b * D_ + d], s4);
  }
}

// ---------------- classifier head (tiny) ----------------
__global__ __launch_bounds__(128) void k_cls(
    const float* __restrict__ zp_accum,
    const float* __restrict__ Wc1, const float* __restrict__ bc1,
    const float* __restrict__ g1, const float* __restrict__ t1,
    const float* __restrict__ Wc2, const float* __restrict__ bc2,
    const float* __restrict__ g2, const float* __restrict__ t2,
    const float* __restrict__ Wc3, const float* __restrict__ bc3,
    float* __restrict__ out) {
  __shared__ float z[512];
  __shared__ float c1s[128];
  __shared__ float c2s[64];
  __shared__ float red[128];
  int b = blockIdx.x, t = threadIdx.x;
  #pragma unroll
  for (int k = 0; k < 4; ++k) {
    int d = t + k * 128;
    float v = zp_accum[b * 512 + d] * (1.f / 1024.f);
    z[d] = v;
    out[128 + b * 512 + d] = v;   // z_pooled output region
  }
  __syncthreads();
  // stage 1: [512]->[128] + LN + relu
  float y = bc1[t];
  for (int d = 0; d < 512; ++d) y += z[d] * Wc1[d * 128 + t];
  red[t] = y;
  __syncthreads();
  float mu = 0.f;
  for (int k = 0; k < 128; ++k) mu += red[k];
  mu *= (1.f / 128.f);
  float var = 0.f;
  for (int k = 0; k < 128; ++k) { float dd = red[k] - mu; var += dd * dd; }
  var *= (1.f / 128.f);
  float c = (y - mu) * rsqrtf(var + LN_EPS) * g1[t] + t1[t];
  c1s[t] = c > 0.f ? c : 0.f;
  __syncthreads();
  // stage 2: [128]->[64] + LN + relu
  if (t < 64) {
    float y2 = bc2[t];
    for (int k = 0; k < 128; ++k) y2 += c1s[k] * Wc2[k * 64 + t];
    red[t] = y2;
  }
  __syncthreads();
  if (t < 64) {
    float mu2 = 0.f;
    for (int k = 0; k < 64; ++k) mu2 += red[k];
    mu2 *= (1.f / 64.f);
    float v2 = 0.f;
    for (int k = 0; k < 64; ++k) { float dd = red[k] - mu2; v2 += dd * dd; }
    v2 *= (1.f / 64.f);
    float cc = (red[t] - mu2) * rsqrtf(v2 + LN_EPS) * g2[t] + t2[t];
    c2s[t] = cc > 0.f ? cc : 0.f;
  }
  __syncthreads();
  if (t < 4) {
    float y3 = bc3[t];
    for (int k = 0; k < 64; ++k) y3 += c2s[k] * Wc3[k * 4 + t];
    out[b * 4 + t] = y3;
  }
}

extern "C" void kernel_launch(void* const* d_in, const int* in_sizes, int n_in,
                              void* d_out, int out_size, void* d_ws, size_t ws_size,
                              hipStream_t stream) {
  const float* A   = (const float*)d_in[0];
  const float* W1  = (const float*)d_in[1];
  const float* b1  = (const float*)d_in[2];
  const float* W2  = (const float*)d_in[3];
  const float* b2  = (const float*)d_in[4];
  const float* lng = (const float*)d_in[5];
  const float* lnb = (const float*)d_in[6];
  const float* Wc1 = (const float*)d_in[7];
  const float* bc1 = (const float*)d_in[8];
  const float* g1  = (const float*)d_in[9];
  const float* t1  = (const float*)d_in[10];
  const float* Wc2 = (const float*)d_in[11];
  const float* bc2 = (const float*)d_in[12];
  const float* g2  = (const float*)d_in[13];
  const float* t2  = (const float*)d_in[14];
  const float* Wc3 = (const float*)d_in[15];
  const float* bc3 = (const float*)d_in[16];
  float* out = (float*)d_out;

  char* ws = (char*)d_ws;
  size_t off = 0;
  auto alloc = [&](size_t bytes) {
    char* p = ws + off;
    off += (bytes + 255) & ~(size_t)255;
    return p;
  };
  float* dis = (float*)alloc((size_t)B_ * N_ * 4);
  bf16* Anbf = (bf16*)alloc((size_t)B_ * N_ * N_ * 2);
  bf16* W1bf = (bf16*)alloc((size_t)N_ * D_ * 2);
  bf16* W2bf = (bf16*)alloc((size_t)D_ * D_ * 2);
  bf16* T12  = (bf16*)alloc((size_t)B_ * N_ * D_ * 2);  // T1, later T2
  bf16* H1   = (bf16*)alloc((size_t)B_ * N_ * D_ * 2);
  bf16* Abf  = (bf16*)alloc((size_t)B_ * N_ * N_ * 2);  // later reused as H2
  bf16* H2   = Abf;  // Abf dead after GEMM1; reuse region
  float* zp  = (float*)alloc((size_t)B_ * D_ * 4);

  k_deg<<<B_ * N_ / 256, 256, 0, stream>>>(A, dis);
  k_build<<<dim3(16, 16, B_), 256, 0, stream>>>(A, dis, Abf, Anbf);
  k_castw<<<(N_ * D_ + D_ * D_) / 256, 256, 0, stream>>>(W1, W2, W1bf, W2bf);
  // GEMM1: T1 = Abf @ W1bf            [1024x1024]@[1024x512]
  k_gemm<false, false><<<dim3(4, 8, B_), 256, 0, stream>>>(
      Abf, (size_t)N_ * N_, W1bf, 0, T12, (size_t)N_ * D_, nullptr, D_, N_);
  // GEMM2: H1 = relu(An @ T1 + b1)    [1024x1024]@[1024x512]
  k_gemm<true, true><<<dim3(4, 8, B_), 256, 0, stream>>>(
      Anbf, (size_t)N_ * N_, T12, (size_t)N_ * D_, H1, (size_t)N_ * D_, b1, D_, N_);
  // GEMM3: T2 = H1 @ W2bf             [1024x512]@[512x512]
  k_gemm<false, false><<<dim3(4, 8, B_), 256, 0, stream>>>(
      H1, (size_t)N_ * D_, W2bf, 0, T12, (size_t)N_ * D_, nullptr, D_, D_);
  // GEMM4: H2 = An @ T2 + b2          [1024x1024]@[1024x512]
  k_gemm<true, false><<<dim3(4, 8, B_), 256, 0, stream>>>(
      Anbf, (size_t)N_ * N_, T12, (size_t)N_ * D_, H2, (size_t)N_ * D_, b2, D_, N_);
  hipMemsetAsync(zp, 0, (size_t)B_ * D_ * 4, stream);
  k_lnpool<<<dim3(16, B_), 256, 0, stream>>>(H2, lng, lnb, zp);
  k_cls<<<B_, 128, 0, stream>>>(zp, Wc1, bc1, g1, t1, Wc2, bc2, g2, t2, Wc3, bc3, out);
}

// Round 2
// 542.524 us; speedup vs baseline: 1.2635x; 1.2635x over previous
//
#include <hip/hip_runtime.h>
#include <hip/hip_bf16.h>

#define B_ 32
#define N_ 1024
#define D_ 512
#define LN_EPS 1e-5f

using bf16 = __bf16;
using bf16x8 = __attribute__((ext_vector_type(8))) __bf16;
using floatx4 = __attribute__((ext_vector_type(4))) float;

__device__ __forceinline__ void gld16(const bf16* gp, bf16* lp) {
  __builtin_amdgcn_global_load_lds(
      (const __attribute__((address_space(1))) void*)gp,
      (__attribute__((address_space(3))) void*)lp, 16, 0, 0);
}

// ---------------- deg (partial col sums via atomics) ----------------
__global__ __launch_bounds__(256) void k_deg(const float* __restrict__ A,
                                             float* __restrict__ deg) {
  int b = blockIdx.y;
  int i0 = blockIdx.x * 32;          // 32 rows per block
  int t = threadIdx.x;               // owns cols 4t..4t+3
  const float* p = A + (size_t)b * N_ * N_ + (size_t)i0 * N_ + t * 4;
  float4 acc = {0.f, 0.f, 0.f, 0.f};
  #pragma unroll 4
  for (int i = 0; i < 32; ++i) {
    float4 v = *(const float4*)(p + (size_t)i * N_);
    acc.x += v.x; acc.y += v.y; acc.z += v.z; acc.w += v.w;
  }
  float* d = deg + b * N_ + t * 4;
  atomicAdd(d + 0, acc.x); atomicAdd(d + 1, acc.y);
  atomicAdd(d + 2, acc.z); atomicAdd(d + 3, acc.w);
}

__global__ __launch_bounds__(256) void k_rsqrt(float* __restrict__ d) {
  int i = blockIdx.x * 256 + threadIdx.x;
  float v = d[i];
  d[i] = v > 0.f ? rsqrtf(v) : 0.f;
}

// ------------- build Abf (straight cast) + Anbf (transpose*dis*dis) -------------
__global__ __launch_bounds__(256) void k_build(const float* __restrict__ A,
                                               const float* __restrict__ dis,
                                               bf16* __restrict__ Abf,
                                               bf16* __restrict__ Anbf) {
  __shared__ float tile[64][65];
  int b = blockIdx.z;
  int i0 = blockIdx.x * 64;   // i range (cols of A read, rows of An)
  int j0 = blockIdx.y * 64;   // j range (rows of A read)
  int t = threadIdx.x;
  const float* Ab = A + (size_t)b * N_ * N_;
  bf16* Abfb = Abf + (size_t)b * N_ * N_;
  bf16* Anb = Anbf + (size_t)b * N_ * N_;
  #pragma unroll
  for (int cc = 0; cc < 4; ++cc) {
    int chunk = cc * 256 + t;       // 0..1023
    int r = chunk >> 4;             // 0..63 (row j offset)
    int c4 = (chunk & 15) << 2;     // 0..60
    const float4 v = *(const float4*)(Ab + (size_t)(j0 + r) * N_ + i0 + c4);
    tile[r][c4 + 0] = v.x; tile[r][c4 + 1] = v.y;
    tile[r][c4 + 2] = v.z; tile[r][c4 + 3] = v.w;
    bf16* dst = Abfb + (size_t)(j0 + r) * N_ + i0 + c4;
    dst[0] = (bf16)v.x; dst[1] = (bf16)v.y; dst[2] = (bf16)v.z; dst[3] = (bf16)v.w;
  }
  __syncthreads();
  const float* disb = dis + b * N_;
  #pragma unroll
  for (int cc = 0; cc < 4; ++cc) {
    int chunk = cc * 256 + t;
    int ii = chunk >> 4;            // 0..63 (out row offset)
    int jj4 = (chunk & 15) << 2;
    float di = disb[i0 + ii];
    bf16* dst = Anb + (size_t)(i0 + ii) * N_ + j0 + jj4;
    #pragma unroll
    for (int e = 0; e < 4; ++e) {
      float v = tile[jj4 + e][ii] * di * disb[j0 + jj4 + e];
      dst[e] = (bf16)v;
    }
  }
}

// ---------------- fp32 -> bf16 transposed cast (weights) ----------------
// in: [R x C] fp32, out: [C x R] bf16
__global__ __launch_bounds__(256) void k_transpose(const float* __restrict__ in,
                                                   bf16* __restrict__ out,
                                                   int R, int C) {
  __shared__ float tile[64][65];
  int c0 = blockIdx.x * 64;
  int r0 = blockIdx.y * 64;
  int t = threadIdx.x;
  #pragma unroll
  for (int cc = 0; cc < 4; ++cc) {
    int idx = cc * 256 + t;
    int r = idx >> 4, c4 = (idx & 15) << 2;
    const float4 v = *(const float4*)(in + (size_t)(r0 + r) * C + c0 + c4);
    tile[r][c4 + 0] = v.x; tile[r][c4 + 1] = v.y;
    tile[r][c4 + 2] = v.z; tile[r][c4 + 3] = v.w;
  }
  __syncthreads();
  #pragma unroll
  for (int cc = 0; cc < 4; ++cc) {
    int idx = cc * 256 + t;
    int c = idx >> 4, r4 = (idx & 15) << 2;
    bf16* dst = out + (size_t)(c0 + c) * R + r0 + r4;
    #pragma unroll
    for (int e = 0; e < 4; ++e) dst[e] = (bf16)tile[r4 + e][c];
  }
}

// --------- MFMA GEMM (m97 structure): C[M,Nn] = A[M,K] @ Bt[Nn,K]^T ----------
// A, Bt row-major with row stride K. 128x128 tile, BK=32, 4 waves.
template <bool BIAS, bool RELU>
__global__ __launch_bounds__(256) void k_gemm(
    const bf16* __restrict__ Abase, size_t strideA,
    const bf16* __restrict__ Btbase, size_t strideBt,
    bf16* __restrict__ Cbase, size_t strideC,
    const float* __restrict__ bias, int Nn, int K) {
  __shared__ bf16 sA[128 * 32];
  __shared__ bf16 sB[128 * 32];
  int b = blockIdx.z;
  int n0 = blockIdx.x * 128;
  int m0 = blockIdx.y * 128;
  const bf16* A = Abase + (size_t)b * strideA;
  const bf16* Bt = Btbase + (size_t)b * strideBt;
  int t = threadIdx.x;
  int lane = t & 63, wid = t >> 6;
  int wm = (wid >> 1) * 64, wn = (wid & 1) * 64;
  int l16 = lane & 15, q = lane >> 4;
  int lrow = lane >> 2;            // 0..15 (row within 16-row segment)
  int lcol = (lane & 3) * 8;       // 0,8,16,24 (k-chunk)

  floatx4 acc[4][4];
  #pragma unroll
  for (int i = 0; i < 4; ++i)
    #pragma unroll
    for (int j = 0; j < 4; ++j) acc[i][j] = (floatx4){0.f, 0.f, 0.f, 0.f};

  // this wave stages segments wid*2 and wid*2+1 of each tile (16 rows each)
  const bf16* agp = A + (size_t)(m0 + wid * 32 + lrow) * K + lcol;
  const bf16* bgp = Bt + (size_t)(n0 + wid * 32 + lrow) * K + lcol;
  bf16* alp = &sA[wid * 1024 + lane * 8];
  bf16* blp = &sB[wid * 1024 + lane * 8];

  for (int kt = 0; kt < K; kt += 32) {
    gld16(agp + kt, alp);
    gld16(agp + (size_t)16 * K + kt, alp + 512);
    gld16(bgp + kt, blp);
    gld16(bgp + (size_t)16 * K + kt, blp + 512);
    __syncthreads();

    bf16x8 af[4], bfr[4];
    #pragma unroll
    for (int mt = 0; mt < 4; ++mt)
      af[mt] = *(const bf16x8*)(&sA[(wm + mt * 16 + l16) * 32 + q * 8]);
    #pragma unroll
    for (int nt = 0; nt < 4; ++nt)
      bfr[nt] = *(const bf16x8*)(&sB[(wn + nt * 16 + l16) * 32 + q * 8]);
    #pragma unroll
    for (int mt = 0; mt < 4; ++mt)
      #pragma unroll
      for (int nt = 0; nt < 4; ++nt)
        acc[mt][nt] = __builtin_amdgcn_mfma_f32_16x16x32_bf16(
            af[mt], bfr[nt], acc[mt][nt], 0, 0, 0);
    __syncthreads();
  }

  bf16* C = Cbase + (size_t)b * strideC;
  #pragma unroll
  for (int mt = 0; mt < 4; ++mt)
    #pragma unroll
    for (int nt = 0; nt < 4; ++nt)
      #pragma unroll
      for (int r = 0; r < 4; ++r) {
        int row = m0 + wm + mt * 16 + q * 4 + r;
        int col = n0 + wn + nt * 16 + l16;
        float v = acc[mt][nt][r];
        if (BIAS) v += bias[col];
        if (RELU) v = v > 0.f ? v : 0.f;
        C[(size_t)row * Nn + col] = (bf16)v;
      }
}

// ---------------- LayerNorm over D + mean-pool over N (accumulate) ----------------
__global__ __launch_bounds__(256) void k_lnpool(const bf16* __restrict__ H2,
                                                const float* __restrict__ g,
                                                const float* __restrict__ be,
                                                float* __restrict__ zp_accum) {
  int b = blockIdx.y;
  int r0 = blockIdx.x * 64;
  int t = threadIdx.x, lane = t & 63, w = t >> 6;
  float ge[8], bee[8];
  #pragma unroll
  for (int e = 0; e < 8; ++e) { ge[e] = g[lane * 8 + e]; bee[e] = be[lane * 8 + e]; }
  float acc[8] = {0, 0, 0, 0, 0, 0, 0, 0};
  for (int rr = 0; rr < 16; ++rr) {
    int row = r0 + w * 16 + rr;
    const bf16* p = H2 + ((size_t)b * N_ + row) * D_ + lane * 8;
    bf16x8 hv = *(const bf16x8*)p;
    float x[8];
    float s = 0.f;
    #pragma unroll
    for (int e = 0; e < 8; ++e) { x[e] = (float)hv[e]; s += x[e]; }
    #pragma unroll
    for (int off = 32; off; off >>= 1) s += __shfl_xor(s, off);
    float mu = s * (1.f / 512.f);
    float ss = 0.f;
    #pragma unroll
    for (int e = 0; e < 8; ++e) { float d = x[e] - mu; ss += d * d; }
    #pragma unroll
    for (int off = 32; off; off >>= 1) ss += __shfl_xor(ss, off);
    float rs = rsqrtf(ss * (1.f / 512.f) + LN_EPS);
    #pragma unroll
    for (int e = 0; e < 8; ++e) acc[e] += (x[e] - mu) * rs * ge[e] + bee[e];
  }
  __shared__ float part[4][512];
  #pragma unroll
  for (int e = 0; e < 8; ++e) part[w][lane * 8 + e] = acc[e];
  __syncthreads();
  #pragma unroll
  for (int k = 0; k < 2; ++k) {
    int d = t + k * 256;
    float s4 = part[0][d] + part[1][d] + part[2][d] + part[3][d];
    atomicAdd(&zp_accum[b * D_ + d], s4);
  }
}

// ---------------- classifier head (tiny) ----------------
__global__ __launch_bounds__(128) void k_cls(
    const float* __restrict__ zp_accum,
    const float* __restrict__ Wc1, const float* __restrict__ bc1,
    const float* __restrict__ g1, const float* __restrict__ t1,
    const float* __restrict__ Wc2, const float* __restrict__ bc2,
    const float* __restrict__ g2, const float* __restrict__ t2,
    const float* __restrict__ Wc3, const float* __restrict__ bc3,
    float* __restrict__ out) {
  __shared__ float z[512];
  __shared__ float c1s[128];
  __shared__ float c2s[64];
  __shared__ float red[128];
  int b = blockIdx.x, t = threadIdx.x;
  #pragma unroll
  for (int k = 0; k < 4; ++k) {
    int d = t + k * 128;
    float v = zp_accum[b * 512 + d] * (1.f / 1024.f);
    z[d] = v;
    out[128 + b * 512 + d] = v;   // z_pooled output region
  }
  __syncthreads();
  float y = bc1[t];
  for (int d = 0; d < 512; ++d) y += z[d] * Wc1[d * 128 + t];
  red[t] = y;
  __syncthreads();
  float mu = 0.f;
  for (int k = 0; k < 128; ++k) mu += red[k];
  mu *= (1.f / 128.f);
  float var = 0.f;
  for (int k = 0; k < 128; ++k) { float dd = red[k] - mu; var += dd * dd; }
  var *= (1.f / 128.f);
  float c = (y - mu) * rsqrtf(var + LN_EPS) * g1[t] + t1[t];
  c1s[t] = c > 0.f ? c : 0.f;
  __syncthreads();
  if (t < 64) {
    float y2 = bc2[t];
    for (int k = 0; k < 128; ++k) y2 += c1s[k] * Wc2[k * 64 + t];
    red[t] = y2;
  }
  __syncthreads();
  if (t < 64) {
    float mu2 = 0.f;
    for (int k = 0; k < 64; ++k) mu2 += red[k];
    mu2 *= (1.f / 64.f);
    float v2 = 0.f;
    for (int k = 0; k < 64; ++k) { float dd = red[k] - mu2; v2 += dd * dd; }
    v2 *= (1.f / 64.f);
    float cc = (red[t] - mu2) * rsqrtf(v2 + LN_EPS) * g2[t] + t2[t];
    c2s[t] = cc > 0.f ? cc : 0.f;
  }
  __syncthreads();
  if (t < 4) {
    float y3 = bc3[t];
    for (int k = 0; k < 64; ++k) y3 += c2s[k] * Wc3[k * 4 + t];
    out[b * 4 + t] = y3;
  }
}

extern "C" void kernel_launch(void* const* d_in, const int* in_sizes, int n_in,
                              void* d_out, int out_size, void* d_ws, size_t ws_size,
                              hipStream_t stream) {
  const float* A   = (const float*)d_in[0];
  const float* W1  = (const float*)d_in[1];
  const float* b1  = (const float*)d_in[2];
  const float* W2  = (const float*)d_in[3];
  const float* b2  = (const float*)d_in[4];
  const float* lng = (const float*)d_in[5];
  const float* lnb = (const float*)d_in[6];
  const float* Wc1 = (const float*)d_in[7];
  const float* bc1 = (const float*)d_in[8];
  const float* g1  = (const float*)d_in[9];
  const float* t1  = (const float*)d_in[10];
  const float* Wc2 = (const float*)d_in[11];
  const float* bc2 = (const float*)d_in[12];
  const float* g2  = (const float*)d_in[13];
  const float* t2  = (const float*)d_in[14];
  const float* Wc3 = (const float*)d_in[15];
  const float* bc3 = (const float*)d_in[16];
  float* out = (float*)d_out;

  char* ws = (char*)d_ws;
  size_t off = 0;
  auto alloc = [&](size_t bytes) {
    char* p = ws + off;
    off += (bytes + 255) & ~(size_t)255;
    return p;
  };
  float* dis  = (float*)alloc((size_t)B_ * N_ * 4);          // deg, then rsqrt'd
  bf16* Anbf  = (bf16*)alloc((size_t)B_ * N_ * N_ * 2);      // 64 MB
  bf16* W1t   = (bf16*)alloc((size_t)D_ * N_ * 2);           // [512 x 1024]
  bf16* W2t   = (bf16*)alloc((size_t)D_ * D_ * 2);           // [512 x 512]
  bf16* T12t  = (bf16*)alloc((size_t)B_ * D_ * N_ * 2);      // T1t then T2t [b][512][1024]
  bf16* H1    = (bf16*)alloc((size_t)B_ * N_ * D_ * 2);      // [b][1024][512]
  bf16* Abf   = (bf16*)alloc((size_t)B_ * N_ * N_ * 2);      // later reused as H2
  bf16* H2    = Abf;                                          // Abf dead after GEMM1
  float* zp   = (float*)alloc((size_t)B_ * D_ * 4);

  hipMemsetAsync(dis, 0, (size_t)B_ * N_ * 4, stream);
  hipMemsetAsync(zp, 0, (size_t)B_ * D_ * 4, stream);

  k_deg<<<dim3(32, B_), 256, 0, stream>>>(A, dis);
  k_rsqrt<<<B_ * N_ / 256, 256, 0, stream>>>(dis);
  k_build<<<dim3(16, 16, B_), 256, 0, stream>>>(A, dis, Abf, Anbf);
  k_transpose<<<dim3(8, 16), 256, 0, stream>>>(W1, W1t, N_, D_);   // [1024x512] -> [512x1024]
  k_transpose<<<dim3(8, 8), 256, 0, stream>>>(W2, W2t, D_, D_);    // [512x512] -> [512x512]

  // G1: T1t[512,1024] = W1t[512,1024] @ Abf[1024,1024]^T   (T1 = A @ W1, transposed)
  k_gemm<false, false><<<dim3(8, 4, B_), 256, 0, stream>>>(
      W1t, 0, Abf, (size_t)N_ * N_, T12t, (size_t)D_ * N_, nullptr, N_, N_);
  // G2: H1[1024,512] = relu(An[1024,1024] @ T1t[512,1024]^T + b1)
  k_gemm<true, true><<<dim3(4, 8, B_), 256, 0, stream>>>(
      Anbf, (size_t)N_ * N_, T12t, (size_t)D_ * N_, H1, (size_t)N_ * D_, b1, D_, N_);
  // G3: T2t[512,1024] = W2t[512,512] @ H1[1024,512]^T      (T2 = H1 @ W2, transposed)
  k_gemm<false, false><<<dim3(8, 4, B_), 256, 0, stream>>>(
      W2t, 0, H1, (size_t)N_ * D_, T12t, (size_t)D_ * N_, nullptr, N_, D_);
  // G4: H2[1024,512] = An[1024,1024] @ T2t[512,1024]^T + b2
  k_gemm<true, false><<<dim3(4, 8, B_), 256, 0, stream>>>(
      Anbf, (size_t)N_ * N_, T12t, (size_t)D_ * N_, H2, (size_t)N_ * D_, b2, D_, N_);

  k_lnpool<<<dim3(16, B_), 256, 0, stream>>>(H2, lng, lnb, zp);
  k_cls<<<B_, 128, 0, stream>>>(zp, Wc1, bc1, g1, t1, Wc2, bc2, g2, t2, Wc3, bc3, out);
}

// Round 3
// 459.544 us; speedup vs baseline: 1.4916x; 1.1806x over previous
//
#include <hip/hip_runtime.h>
#include <hip/hip_bf16.h>

#define B_ 32
#define N_ 1024
#define D_ 512
#define LN_EPS 1e-5f

using bf16 = __bf16;
using bf16x4 = __attribute__((ext_vector_type(4))) __bf16;
using bf16x8 = __attribute__((ext_vector_type(8))) __bf16;
using floatx4 = __attribute__((ext_vector_type(4))) float;

__device__ __forceinline__ void gld16(const bf16* gp, bf16* lp) {
  __builtin_amdgcn_global_load_lds(
      (const __attribute__((address_space(1))) void*)gp,
      (__attribute__((address_space(3))) void*)lp, 16, 0, 0);
}

// ---------------- deg (partial col sums via atomics) + Abf cast ----------------
__global__ __launch_bounds__(256) void k_deg(const float* __restrict__ A,
                                             float* __restrict__ deg,
                                             bf16* __restrict__ Abf) {
  int b = blockIdx.y;
  int i0 = blockIdx.x * 32;          // 32 rows per block
  int t = threadIdx.x;               // owns cols 4t..4t+3
  const float* p = A + (size_t)b * N_ * N_ + (size_t)i0 * N_ + t * 4;
  bf16* op = Abf + (size_t)b * N_ * N_ + (size_t)i0 * N_ + t * 4;
  float4 acc = {0.f, 0.f, 0.f, 0.f};
  #pragma unroll 4
  for (int i = 0; i < 32; ++i) {
    float4 v = *(const float4*)(p + (size_t)i * N_);
    acc.x += v.x; acc.y += v.y; acc.z += v.z; acc.w += v.w;
    bf16x4 o = {(bf16)v.x, (bf16)v.y, (bf16)v.z, (bf16)v.w};
    *(bf16x4*)(op + (size_t)i * N_) = o;
  }
  float* d = deg + b * N_ + t * 4;
  atomicAdd(d + 0, acc.x); atomicAdd(d + 1, acc.y);
  atomicAdd(d + 2, acc.z); atomicAdd(d + 3, acc.w);
}

__global__ __launch_bounds__(256) void k_rsqrt(float* __restrict__ d) {
  int i = blockIdx.x * 256 + threadIdx.x;
  float v = d[i];
  d[i] = v > 0.f ? rsqrtf(v) : 0.f;
}

// ------------- build Anbf = transpose(Abf) * dis_i * dis_j -------------
__global__ __launch_bounds__(256) void k_build(const bf16* __restrict__ Abf,
                                               const float* __restrict__ dis,
                                               bf16* __restrict__ Anbf) {
  __shared__ float tile[64][65];
  int b = blockIdx.z;
  int i0 = blockIdx.x * 64;   // i range (cols of A read, rows of An)
  int j0 = blockIdx.y * 64;   // j range (rows of A read)
  int t = threadIdx.x;
  const bf16* Ab = Abf + (size_t)b * N_ * N_;
  bf16* Anb = Anbf + (size_t)b * N_ * N_;
  #pragma unroll
  for (int cc = 0; cc < 4; ++cc) {
    int chunk = cc * 256 + t;       // 0..1023
    int r = chunk >> 4;             // 0..63 (row j offset)
    int c4 = (chunk & 15) << 2;     // 0..60
    bf16x4 v = *(const bf16x4*)(Ab + (size_t)(j0 + r) * N_ + i0 + c4);
    tile[r][c4 + 0] = (float)v[0]; tile[r][c4 + 1] = (float)v[1];
    tile[r][c4 + 2] = (float)v[2]; tile[r][c4 + 3] = (float)v[3];
  }
  __syncthreads();
  const float* disb = dis + b * N_;
  #pragma unroll
  for (int cc = 0; cc < 4; ++cc) {
    int chunk = cc * 256 + t;
    int ii = chunk >> 4;            // 0..63 (out row offset)
    int jj4 = (chunk & 15) << 2;
    float di = disb[i0 + ii];
    bf16x4 o;
    #pragma unroll
    for (int e = 0; e < 4; ++e)
      o[e] = (bf16)(tile[jj4 + e][ii] * di * disb[j0 + jj4 + e]);
    *(bf16x4*)(Anb + (size_t)(i0 + ii) * N_ + j0 + jj4) = o;
  }
}

// ---------------- fp32 -> bf16 transposed cast (weights) ----------------
__global__ __launch_bounds__(256) void k_transpose(const float* __restrict__ in,
                                                   bf16* __restrict__ out,
                                                   int R, int C) {
  __shared__ float tile[64][65];
  int c0 = blockIdx.x * 64;
  int r0 = blockIdx.y * 64;
  int t = threadIdx.x;
  #pragma unroll
  for (int cc = 0; cc < 4; ++cc) {
    int idx = cc * 256 + t;
    int r = idx >> 4, c4 = (idx & 15) << 2;
    const float4 v = *(const float4*)(in + (size_t)(r0 + r) * C + c0 + c4);
    tile[r][c4 + 0] = v.x; tile[r][c4 + 1] = v.y;
    tile[r][c4 + 2] = v.z; tile[r][c4 + 3] = v.w;
  }
  __syncthreads();
  #pragma unroll
  for (int cc = 0; cc < 4; ++cc) {
    int idx = cc * 256 + t;
    int c = idx >> 4, r4 = (idx & 15) << 2;
    bf16* dst = out + (size_t)(c0 + c) * R + r0 + r4;
    #pragma unroll
    for (int e = 0; e < 4; ++e) dst[e] = (bf16)tile[r4 + e][c];
  }
}

// --------- MFMA GEMM: C[M,Nn] = A[M,K] @ Bt[Nn,K]^T ----------
// 128x128 tile, BK=64, 4 waves, XOR-swizzled LDS (conflict-free b128 reads),
// XCD-aware block swizzle (batch -> one XCD for L2 locality).
template <bool BIAS, bool RELU>
__global__ __launch_bounds__(256) void k_gemm(
    const bf16* __restrict__ Abase, size_t strideA,
    const bf16* __restrict__ Btbase, size_t strideBt,
    bf16* __restrict__ Cbase, size_t strideC,
    const float* __restrict__ bias, int Nn, int K) {
  __shared__ bf16 sA[128 * 64];
  __shared__ bf16 sB[128 * 64];
  // XCD swizzle: batch b's blocks all land on XCD b%8 (assumes linear%8 mapping)
  int nxy = gridDim.x * gridDim.y;            // blocks per batch (32 here)
  int L = blockIdx.z * nxy + blockIdx.y * gridDim.x + blockIdx.x;
  int b = (L & 7) + 8 * (L / (nxy * 8));
  int inner = (L >> 3) % nxy;
  int n0 = (inner % gridDim.x) * 128;
  int m0 = (inner / gridDim.x) * 128;

  const bf16* A = Abase + (size_t)b * strideA;
  const bf16* Bt = Btbase + (size_t)b * strideBt;
  int t = threadIdx.x;
  int lane = t & 63, wid = t >> 6;
  int wm = (wid >> 1) * 64, wn = (wid & 1) * 64;
  int l16 = lane & 15, q = lane >> 4;

  // staging: wave `wid` fills rows [wid*32, wid*32+32) of both tiles.
  // slot l of each 8-row window holds chunk (l&7)^(l>>3) of row l>>3
  int rowoff = lane >> 3;                 // 0..7
  int schunk = (lane & 7) ^ rowoff;       // swizzled source chunk
  const bf16* agp = A + (size_t)(m0 + wid * 32 + rowoff) * K + schunk * 8;
  const bf16* bgp = Bt + (size_t)(n0 + wid * 32 + rowoff) * K + schunk * 8;
  bf16* alp = &sA[wid * 2048 + lane * 8];
  bf16* blp = &sB[wid * 2048 + lane * 8];

  // fragment-read swizzled k-chunk offsets (h = k-half of 64)
  int xorb = l16 & 7;
  int co[2] = {(q ^ xorb) * 8, ((q + 4) ^ xorb) * 8};

  floatx4 acc[4][4];
  #pragma unroll
  for (int i = 0; i < 4; ++i)
    #pragma unroll
    for (int j = 0; j < 4; ++j) acc[i][j] = (floatx4){0.f, 0.f, 0.f, 0.f};

  for (int kt = 0; kt < K; kt += 64) {
    #pragma unroll
    for (int s = 0; s < 4; ++s) {
      gld16(agp + (size_t)s * 8 * K + kt, alp + s * 512);
      gld16(bgp + (size_t)s * 8 * K + kt, blp + s * 512);
    }
    __syncthreads();
    #pragma unroll
    for (int h = 0; h < 2; ++h) {
      bf16x8 af[4], bfr[4];
      #pragma unroll
      for (int mt = 0; mt < 4; ++mt)
        af[mt] = *(const bf16x8*)(&sA[(wm + mt * 16 + l16) * 64 + co[h]]);
      #pragma unroll
      for (int nt = 0; nt < 4; ++nt)
        bfr[nt] = *(const bf16x8*)(&sB[(wn + nt * 16 + l16) * 64 + co[h]]);
      #pragma unroll
      for (int mt = 0; mt < 4; ++mt)
        #pragma unroll
        for (int nt = 0; nt < 4; ++nt)
          acc[mt][nt] = __builtin_amdgcn_mfma_f32_16x16x32_bf16(
              af[mt], bfr[nt], acc[mt][nt], 0, 0, 0);
    }
    __syncthreads();
  }

  bf16* C = Cbase + (size_t)b * strideC;
  #pragma unroll
  for (int mt = 0; mt < 4; ++mt)
    #pragma unroll
    for (int nt = 0; nt < 4; ++nt)
      #pragma unroll
      for (int r = 0; r < 4; ++r) {
        int row = m0 + wm + mt * 16 + q * 4 + r;
        int col = n0 + wn + nt * 16 + l16;
        float v = acc[mt][nt][r];
        if (BIAS) v += bias[col];
        if (RELU) v = v > 0.f ? v : 0.f;
        C[(size_t)row * Nn + col] = (bf16)v;
      }
}

// ---------------- LayerNorm over D + mean-pool over N (accumulate) ----------------
__global__ __launch_bounds__(256) void k_lnpool(const bf16* __restrict__ H2,
                                                const float* __restrict__ g,
                                                const float* __restrict__ be,
                                                float* __restrict__ zp_accum) {
  int b = blockIdx.y;
  int r0 = blockIdx.x * 64;
  int t = threadIdx.x, lane = t & 63, w = t >> 6;
  float ge[8], bee[8];
  #pragma unroll
  for (int e = 0; e < 8; ++e) { ge[e] = g[lane * 8 + e]; bee[e] = be[lane * 8 + e]; }
  float acc[8] = {0, 0, 0, 0, 0, 0, 0, 0};
  for (int rr = 0; rr < 16; ++rr) {
    int row = r0 + w * 16 + rr;
    const bf16* p = H2 + ((size_t)b * N_ + row) * D_ + lane * 8;
    bf16x8 hv = *(const bf16x8*)p;
    float x[8];
    float s = 0.f;
    #pragma unroll
    for (int e = 0; e < 8; ++e) { x[e] = (float)hv[e]; s += x[e]; }
    #pragma unroll
    for (int off = 32; off; off >>= 1) s += __shfl_xor(s, off);
    float mu = s * (1.f / 512.f);
    float ss = 0.f;
    #pragma unroll
    for (int e = 0; e < 8; ++e) { float d = x[e] - mu; ss += d * d; }
    #pragma unroll
    for (int off = 32; off; off >>= 1) ss += __shfl_xor(ss, off);
    float rs = rsqrtf(ss * (1.f / 512.f) + LN_EPS);
    #pragma unroll
    for (int e = 0; e < 8; ++e) acc[e] += (x[e] - mu) * rs * ge[e] + bee[e];
  }
  __shared__ float part[4][512];
  #pragma unroll
  for (int e = 0; e < 8; ++e) part[w][lane * 8 + e] = acc[e];
  __syncthreads();
  #pragma unroll
  for (int k = 0; k < 2; ++k) {
    int d = t + k * 256;
    float s4 = part[0][d] + part[1][d] + part[2][d] + part[3][d];
    atomicAdd(&zp_accum[b * D_ + d], s4);
  }
}

// ---------------- classifier head (tiny) ----------------
__global__ __launch_bounds__(128) void k_cls(
    const float* __restrict__ zp_accum,
    const float* __restrict__ Wc1, const float* __restrict__ bc1,
    const float* __restrict__ g1, const float* __restrict__ t1,
    const float* __restrict__ Wc2, const float* __restrict__ bc2,
    const float* __restrict__ g2, const float* __restrict__ t2,
    const float* __restrict__ Wc3, const float* __restrict__ bc3,
    float* __restrict__ out) {
  __shared__ float z[512];
  __shared__ float c1s[128];
  __shared__ float c2s[64];
  __shared__ float red[128];
  int b = blockIdx.x, t = threadIdx.x;
  #pragma unroll
  for (int k = 0; k < 4; ++k) {
    int d = t + k * 128;
    float v = zp_accum[b * 512 + d] * (1.f / 1024.f);
    z[d] = v;
    out[128 + b * 512 + d] = v;   // z_pooled output region
  }
  __syncthreads();
  float y = bc1[t];
  for (int d = 0; d < 512; ++d) y += z[d] * Wc1[d * 128 + t];
  red[t] = y;
  __syncthreads();
  float mu = 0.f;
  for (int k = 0; k < 128; ++k) mu += red[k];
  mu *= (1.f / 128.f);
  float var = 0.f;
  for (int k = 0; k < 128; ++k) { float dd = red[k] - mu; var += dd * dd; }
  var *= (1.f / 128.f);
  float c = (y - mu) * rsqrtf(var + LN_EPS) * g1[t] + t1[t];
  c1s[t] = c > 0.f ? c : 0.f;
  __syncthreads();
  if (t < 64) {
    float y2 = bc2[t];
    for (int k = 0; k < 128; ++k) y2 += c1s[k] * Wc2[k * 64 + t];
    red[t] = y2;
  }
  __syncthreads();
  if (t < 64) {
    float mu2 = 0.f;
    for (int k = 0; k < 64; ++k) mu2 += red[k];
    mu2 *= (1.f / 64.f);
    float v2 = 0.f;
    for (int k = 0; k < 64; ++k) { float dd = red[k] - mu2; v2 += dd * dd; }
    v2 *= (1.f / 64.f);
    float cc = (red[t] - mu2) * rsqrtf(v2 + LN_EPS) * g2[t] + t2[t];
    c2s[t] = cc > 0.f ? cc : 0.f;
  }
  __syncthreads();
  if (t < 4) {
    float y3 = bc3[t];
    for (int k = 0; k < 64; ++k) y3 += c2s[k] * Wc3[k * 4 + t];
    out[b * 4 + t] = y3;
  }
}

extern "C" void kernel_launch(void* const* d_in, const int* in_sizes, int n_in,
                              void* d_out, int out_size, void* d_ws, size_t ws_size,
                              hipStream_t stream) {
  const float* A   = (const float*)d_in[0];
  const float* W1  = (const float*)d_in[1];
  const float* b1  = (const float*)d_in[2];
  const float* W2  = (const float*)d_in[3];
  const float* b2  = (const float*)d_in[4];
  const float* lng = (const float*)d_in[5];
  const float* lnb = (const float*)d_in[6];
  const float* Wc1 = (const float*)d_in[7];
  const float* bc1 = (const float*)d_in[8];
  const float* g1  = (const float*)d_in[9];
  const float* t1  = (const float*)d_in[10];
  const float* Wc2 = (const float*)d_in[11];
  const float* bc2 = (const float*)d_in[12];
  const float* g2  = (const float*)d_in[13];
  const float* t2  = (const float*)d_in[14];
  const float* Wc3 = (const float*)d_in[15];
  const float* bc3 = (const float*)d_in[16];
  float* out = (float*)d_out;

  char* ws = (char*)d_ws;
  size_t off = 0;
  auto alloc = [&](size_t bytes) {
    char* p = ws + off;
    off += (bytes + 255) & ~(size_t)255;
    return p;
  };
  float* dis  = (float*)alloc((size_t)B_ * N_ * 4);          // deg, then rsqrt'd
  bf16* Anbf  = (bf16*)alloc((size_t)B_ * N_ * N_ * 2);      // 64 MB
  bf16* W1t   = (bf16*)alloc((size_t)D_ * N_ * 2);           // [512 x 1024]
  bf16* W2t   = (bf16*)alloc((size_t)D_ * D_ * 2);           // [512 x 512]
  bf16* T12t  = (bf16*)alloc((size_t)B_ * D_ * N_ * 2);      // T1t then T2t
  bf16* H1    = (bf16*)alloc((size_t)B_ * N_ * D_ * 2);      // [b][1024][512]
  bf16* Abf   = (bf16*)alloc((size_t)B_ * N_ * N_ * 2);      // later reused as H2
  bf16* H2    = Abf;                                          // Abf dead after GEMM1
  float* zp   = (float*)alloc((size_t)B_ * D_ * 4);

  hipMemsetAsync(dis, 0, (size_t)B_ * N_ * 4, stream);
  hipMemsetAsync(zp, 0, (size_t)B_ * D_ * 4, stream);

  k_deg<<<dim3(32, B_), 256, 0, stream>>>(A, dis, Abf);
  k_rsqrt<<<B_ * N_ / 256, 256, 0, stream>>>(dis);
  k_build<<<dim3(16, 16, B_), 256, 0, stream>>>(Abf, dis, Anbf);
  k_transpose<<<dim3(8, 16), 256, 0, stream>>>(W1, W1t, N_, D_);   // [1024x512] -> [512x1024]
  k_transpose<<<dim3(8, 8), 256, 0, stream>>>(W2, W2t, D_, D_);    // [512x512] -> [512x512]

  // G1: T1t[512,1024] = W1t[512,1024] @ Abf[1024,1024]^T   (T1 = A @ W1, transposed)
  k_gemm<false, false><<<dim3(8, 4, B_), 256, 0, stream>>>(
      W1t, 0, Abf, (size_t)N_ * N_, T12t, (size_t)D_ * N_, nullptr, N_, N_);
  // G2: H1[1024,512] = relu(An[1024,1024] @ T1t[512,1024]^T + b1)
  k_gemm<true, true><<<dim3(4, 8, B_), 256, 0, stream>>>(
      Anbf, (size_t)N_ * N_, T12t, (size_t)D_ * N_, H1, (size_t)N_ * D_, b1, D_, N_);
  // G3: T2t[512,1024] = W2t[512,512] @ H1[1024,512]^T      (T2 = H1 @ W2, transposed)
  k_gemm<false, false><<<dim3(8, 4, B_), 256, 0, stream>>>(
      W2t, 0, H1, (size_t)N_ * D_, T12t, (size_t)D_ * N_, nullptr, N_, D_);
  // G4: H2[1024,512] = An[1024,1024] @ T2t[512,1024]^T + b2
  k_gemm<true, false><<<dim3(4, 8, B_), 256, 0, stream>>>(
      Anbf, (size_t)N_ * N_, T12t, (size_t)D_ * N_, H2, (size_t)N_ * D_, b2, D_, N_);

  k_lnpool<<<dim3(16, B_), 256, 0, stream>>>(H2, lng, lnb, zp);
  k_cls<<<B_, 128, 0, stream>>>(zp, Wc1, bc1, g1, t1, Wc2, bc2, g2, t2, Wc3, bc3, out);
}

// Round 4
// 430.871 us; speedup vs baseline: 1.5909x; 1.0665x over previous
//
#include <hip/hip_runtime.h>
#include <hip/hip_bf16.h>

#define B_ 32
#define N_ 1024
#define D_ 512
#define LN_EPS 1e-5f

using bf16 = __bf16;
using bf16x4 = __attribute__((ext_vector_type(4))) __bf16;
using bf16x8 = __attribute__((ext_vector_type(8))) __bf16;
using floatx4 = __attribute__((ext_vector_type(4))) float;

__device__ __forceinline__ void gld16(const bf16* gp, bf16* lp) {
  __builtin_amdgcn_global_load_lds(
      (const __attribute__((address_space(1))) void*)gp,
      (__attribute__((address_space(3))) void*)lp, 16, 0, 0);
}

// ---------------- deg (partial col sums via atomics) + Abf cast ----------------
__global__ __launch_bounds__(256) void k_deg(const float* __restrict__ A,
                                             float* __restrict__ deg,
                                             bf16* __restrict__ Abf) {
  int b = blockIdx.y;
  int i0 = blockIdx.x * 128;         // 128 rows per block
  int t = threadIdx.x;               // owns cols 4t..4t+3
  const float* p = A + (size_t)b * N_ * N_ + (size_t)i0 * N_ + t * 4;
  bf16* op = Abf + (size_t)b * N_ * N_ + (size_t)i0 * N_ + t * 4;
  float4 acc = {0.f, 0.f, 0.f, 0.f};
  #pragma unroll 4
  for (int i = 0; i < 128; ++i) {
    float4 v = *(const float4*)(p + (size_t)i * N_);
    acc.x += v.x; acc.y += v.y; acc.z += v.z; acc.w += v.w;
    bf16x4 o = {(bf16)v.x, (bf16)v.y, (bf16)v.z, (bf16)v.w};
    *(bf16x4*)(op + (size_t)i * N_) = o;
  }
  float* d = deg + b * N_ + t * 4;
  atomicAdd(d + 0, acc.x); atomicAdd(d + 1, acc.y);
  atomicAdd(d + 2, acc.z); atomicAdd(d + 3, acc.w);
}

// ------------- build Anbf = transpose(Abf) * rsqrt(deg_i) * rsqrt(deg_j) -------------
__global__ __launch_bounds__(256) void k_build(const bf16* __restrict__ Abf,
                                               const float* __restrict__ deg,
                                               bf16* __restrict__ Anbf) {
  __shared__ float tile[64][65];
  __shared__ float disI[64], disJ[64];
  int b = blockIdx.z;
  int i0 = blockIdx.x * 64;   // i range (cols of A read, rows of An)
  int j0 = blockIdx.y * 64;   // j range (rows of A read)
  int t = threadIdx.x;
  const bf16* Ab = Abf + (size_t)b * N_ * N_;
  bf16* Anb = Anbf + (size_t)b * N_ * N_;
  if (t < 64) {
    float v = deg[b * N_ + i0 + t];
    disI[t] = v > 0.f ? rsqrtf(v) : 0.f;
  } else if (t < 128) {
    float v = deg[b * N_ + j0 + (t - 64)];
    disJ[t - 64] = v > 0.f ? rsqrtf(v) : 0.f;
  }
  #pragma unroll
  for (int cc = 0; cc < 4; ++cc) {
    int chunk = cc * 256 + t;       // 0..1023
    int r = chunk >> 4;             // 0..63 (row j offset)
    int c4 = (chunk & 15) << 2;     // 0..60
    bf16x4 v = *(const bf16x4*)(Ab + (size_t)(j0 + r) * N_ + i0 + c4);
    tile[r][c4 + 0] = (float)v[0]; tile[r][c4 + 1] = (float)v[1];
    tile[r][c4 + 2] = (float)v[2]; tile[r][c4 + 3] = (float)v[3];
  }
  __syncthreads();
  #pragma unroll
  for (int cc = 0; cc < 4; ++cc) {
    int chunk = cc * 256 + t;
    int ii = chunk >> 4;            // 0..63 (out row offset)
    int jj4 = (chunk & 15) << 2;
    float di = disI[ii];
    bf16x4 o;
    #pragma unroll
    for (int e = 0; e < 4; ++e)
      o[e] = (bf16)(tile[jj4 + e][ii] * di * disJ[jj4 + e]);
    *(bf16x4*)(Anb + (size_t)(i0 + ii) * N_ + j0 + jj4) = o;
  }
}

// -------- fp32 -> bf16 transposed cast for BOTH weights, one dispatch --------
// blocks 0..127: W1 [1024x512] -> W1t [512x1024]; blocks 128..191: W2 [512x512]
__global__ __launch_bounds__(256) void k_transpose(const float* __restrict__ W1,
                                                   bf16* __restrict__ W1t,
                                                   const float* __restrict__ W2,
                                                   bf16* __restrict__ W2t) {
  __shared__ float tile[64][65];
  int blk = blockIdx.x;
  const float* in; bf16* outp; int R, C, c0, r0;
  if (blk < 128) {
    in = W1; outp = W1t; R = N_; C = D_;
    c0 = (blk & 7) * 64; r0 = (blk >> 3) * 64;
  } else {
    blk -= 128;
    in = W2; outp = W2t; R = D_; C = D_;
    c0 = (blk & 7) * 64; r0 = (blk >> 3) * 64;
  }
  int t = threadIdx.x;
  #pragma unroll
  for (int cc = 0; cc < 4; ++cc) {
    int idx = cc * 256 + t;
    int r = idx >> 4, c4 = (idx & 15) << 2;
    const float4 v = *(const float4*)(in + (size_t)(r0 + r) * C + c0 + c4);
    tile[r][c4 + 0] = v.x; tile[r][c4 + 1] = v.y;
    tile[r][c4 + 2] = v.z; tile[r][c4 + 3] = v.w;
  }
  __syncthreads();
  #pragma unroll
  for (int cc = 0; cc < 4; ++cc) {
    int idx = cc * 256 + t;
    int c = idx >> 4, r4 = (idx & 15) << 2;
    bf16* dst = outp + (size_t)(c0 + c) * R + r0 + r4;
    #pragma unroll
    for (int e = 0; e < 4; ++e) dst[e] = (bf16)tile[r4 + e][c];
  }
}

// --------- MFMA GEMM: C[M,Nn] = A[M,K] @ Bt[Nn,K]^T ----------
// 128x128 tile, BK=64, 4 waves, XOR-swizzled LDS, XCD-aware block swizzle.
// __launch_bounds__(256,4): force <=128 unified regs/wave -> 4 blocks/CU.
template <bool BIAS, bool RELU>
__global__ __launch_bounds__(256, 4) void k_gemm(
    const bf16* __restrict__ Abase, size_t strideA,
    const bf16* __restrict__ Btbase, size_t strideBt,
    bf16* __restrict__ Cbase, size_t strideC,
    const float* __restrict__ bias, int Nn, int K) {
  __shared__ bf16 sA[128 * 64];
  __shared__ bf16 sB[128 * 64];
  // XCD swizzle: batch b's blocks all land on XCD b%8 (assumes linear%8 mapping)
  int nxy = gridDim.x * gridDim.y;            // blocks per batch (32 here)
  int L = blockIdx.z * nxy + blockIdx.y * gridDim.x + blockIdx.x;
  int b = (L & 7) + 8 * (L / (nxy * 8));
  int inner = (L >> 3) % nxy;
  int n0 = (inner % gridDim.x) * 128;
  int m0 = (inner / gridDim.x) * 128;

  const bf16* A = Abase + (size_t)b * strideA;
  const bf16* Bt = Btbase + (size_t)b * strideBt;
  int t = threadIdx.x;
  int lane = t & 63, wid = t >> 6;
  int wm = (wid >> 1) * 64, wn = (wid & 1) * 64;
  int l16 = lane & 15, q = lane >> 4;

  // staging: wave `wid` fills rows [wid*32, wid*32+32) of both tiles.
  // slot l of each 8-row window holds chunk (l&7)^(l>>3) of row l>>3
  int rowoff = lane >> 3;                 // 0..7
  int schunk = (lane & 7) ^ rowoff;       // swizzled source chunk
  const bf16* agp = A + (size_t)(m0 + wid * 32 + rowoff) * K + schunk * 8;
  const bf16* bgp = Bt + (size_t)(n0 + wid * 32 + rowoff) * K + schunk * 8;
  bf16* alp = &sA[wid * 2048 + lane * 8];
  bf16* blp = &sB[wid * 2048 + lane * 8];

  int xorb = l16 & 7;

  floatx4 acc[4][4];
  #pragma unroll
  for (int i = 0; i < 4; ++i)
    #pragma unroll
    for (int j = 0; j < 4; ++j) acc[i][j] = (floatx4){0.f, 0.f, 0.f, 0.f};

  for (int kt = 0; kt < K; kt += 64) {
    #pragma unroll
    for (int s = 0; s < 4; ++s) {
      gld16(agp + (size_t)s * 8 * K + kt, alp + s * 512);
      gld16(bgp + (size_t)s * 8 * K + kt, blp + s * 512);
    }
    __syncthreads();
    #pragma unroll
    for (int h = 0; h < 2; ++h) {
      int cko = ((q + 4 * h) ^ xorb) * 8;   // recomputed (reg slim)
      bf16x8 af[4], bfr[4];
      #pragma unroll
      for (int mt = 0; mt < 4; ++mt)
        af[mt] = *(const bf16x8*)(&sA[(wm + mt * 16 + l16) * 64 + cko]);
      #pragma unroll
      for (int nt = 0; nt < 4; ++nt)
        bfr[nt] = *(const bf16x8*)(&sB[(wn + nt * 16 + l16) * 64 + cko]);
      #pragma unroll
      for (int mt = 0; mt < 4; ++mt)
        #pragma unroll
        for (int nt = 0; nt < 4; ++nt)
          acc[mt][nt] = __builtin_amdgcn_mfma_f32_16x16x32_bf16(
              af[mt], bfr[nt], acc[mt][nt], 0, 0, 0);
    }
    __syncthreads();
  }

  bf16* C = Cbase + (size_t)b * strideC;
  #pragma unroll
  for (int mt = 0; mt < 4; ++mt)
    #pragma unroll
    for (int nt = 0; nt < 4; ++nt)
      #pragma unroll
      for (int r = 0; r < 4; ++r) {
        int row = m0 + wm + mt * 16 + q * 4 + r;
        int col = n0 + wn + nt * 16 + l16;
        float v = acc[mt][nt][r];
        if (BIAS) v += bias[col];
        if (RELU) v = v > 0.f ? v : 0.f;
        C[(size_t)row * Nn + col] = (bf16)v;
      }
}

// ---------------- LayerNorm over D + mean-pool over N (accumulate) ----------------
__global__ __launch_bounds__(256) void k_lnpool(const bf16* __restrict__ H2,
                                                const float* __restrict__ g,
                                                const float* __restrict__ be,
                                                float* __restrict__ zp_accum) {
  int b = blockIdx.y;
  int r0 = blockIdx.x * 64;
  int t = threadIdx.x, lane = t & 63, w = t >> 6;
  float ge[8], bee[8];
  #pragma unroll
  for (int e = 0; e < 8; ++e) { ge[e] = g[lane * 8 + e]; bee[e] = be[lane * 8 + e]; }
  float acc[8] = {0, 0, 0, 0, 0, 0, 0, 0};
  for (int rr = 0; rr < 16; ++rr) {
    int row = r0 + w * 16 + rr;
    const bf16* p = H2 + ((size_t)b * N_ + row) * D_ + lane * 8;
    bf16x8 hv = *(const bf16x8*)p;
    float x[8];
    float s = 0.f;
    #pragma unroll
    for (int e = 0; e < 8; ++e) { x[e] = (float)hv[e]; s += x[e]; }
    #pragma unroll
    for (int off = 32; off; off >>= 1) s += __shfl_xor(s, off);
    float mu = s * (1.f / 512.f);
    float ss = 0.f;
    #pragma unroll
    for (int e = 0; e < 8; ++e) { float d = x[e] - mu; ss += d * d; }
    #pragma unroll
    for (int off = 32; off; off >>= 1) ss += __shfl_xor(ss, off);
    float rs = rsqrtf(ss * (1.f / 512.f) + LN_EPS);
    #pragma unroll
    for (int e = 0; e < 8; ++e) acc[e] += (x[e] - mu) * rs * ge[e] + bee[e];
  }
  __shared__ float part[4][512];
  #pragma unroll
  for (int e = 0; e < 8; ++e) part[w][lane * 8 + e] = acc[e];
  __syncthreads();
  #pragma unroll
  for (int k = 0; k < 2; ++k) {
    int d = t + k * 256;
    float s4 = part[0][d] + part[1][d] + part[2][d] + part[3][d];
    atomicAdd(&zp_accum[b * D_ + d], s4);
  }
}

// ---------------- classifier head (tiny) ----------------
__global__ __launch_bounds__(128) void k_cls(
    const float* __restrict__ zp_accum,
    const float* __restrict__ Wc1, const float* __restrict__ bc1,
    const float* __restrict__ g1, const float* __restrict__ t1,
    const float* __restrict__ Wc2, const float* __restrict__ bc2,
    const float* __restrict__ g2, const float* __restrict__ t2,
    const float* __restrict__ Wc3, const float* __restrict__ bc3,
    float* __restrict__ out) {
  __shared__ float z[512];
  __shared__ float c1s[128];
  __shared__ float c2s[64];
  __shared__ float red[128];
  int b = blockIdx.x, t = threadIdx.x;
  #pragma unroll
  for (int k = 0; k < 4; ++k) {
    int d = t + k * 128;
    float v = zp_accum[b * 512 + d] * (1.f / 1024.f);
    z[d] = v;
    out[128 + b * 512 + d] = v;   // z_pooled output region
  }
  __syncthreads();
  float y = bc1[t];
  for (int d = 0; d < 512; ++d) y += z[d] * Wc1[d * 128 + t];
  red[t] = y;
  __syncthreads();
  float mu = 0.f;
  for (int k = 0; k < 128; ++k) mu += red[k];
  mu *= (1.f / 128.f);
  float var = 0.f;
  for (int k = 0; k < 128; ++k) { float dd = red[k] - mu; var += dd * dd; }
  var *= (1.f / 128.f);
  float c = (y - mu) * rsqrtf(var + LN_EPS) * g1[t] + t1[t];
  c1s[t] = c > 0.f ? c : 0.f;
  __syncthreads();
  if (t < 64) {
    float y2 = bc2[t];
    for (int k = 0; k < 128; ++k) y2 += c1s[k] * Wc2[k * 64 + t];
    red[t] = y2;
  }
  __syncthreads();
  if (t < 64) {
    float mu2 = 0.f;
    for (int k = 0; k < 64; ++k) mu2 += red[k];
    mu2 *= (1.f / 64.f);
    float v2 = 0.f;
    for (int k = 0; k < 64; ++k) { float dd = red[k] - mu2; v2 += dd * dd; }
    v2 *= (1.f / 64.f);
    float cc = (red[t] - mu2) * rsqrtf(v2 + LN_EPS) * g2[t] + t2[t];
    c2s[t] = cc > 0.f ? cc : 0.f;
  }
  __syncthreads();
  if (t < 4) {
    float y3 = bc3[t];
    for (int k = 0; k < 64; ++k) y3 += c2s[k] * Wc3[k * 4 + t];
    out[b * 4 + t] = y3;
  }
}

extern "C" void kernel_launch(void* const* d_in, const int* in_sizes, int n_in,
                              void* d_out, int out_size, void* d_ws, size_t ws_size,
                              hipStream_t stream) {
  const float* A   = (const float*)d_in[0];
  const float* W1  = (const float*)d_in[1];
  const float* b1  = (const float*)d_in[2];
  const float* W2  = (const float*)d_in[3];
  const float* b2  = (const float*)d_in[4];
  const float* lng = (const float*)d_in[5];
  const float* lnb = (const float*)d_in[6];
  const float* Wc1 = (const float*)d_in[7];
  const float* bc1 = (const float*)d_in[8];
  const float* g1  = (const float*)d_in[9];
  const float* t1  = (const float*)d_in[10];
  const float* Wc2 = (const float*)d_in[11];
  const float* bc2 = (const float*)d_in[12];
  const float* g2  = (const float*)d_in[13];
  const float* t2  = (const float*)d_in[14];
  const float* Wc3 = (const float*)d_in[15];
  const float* bc3 = (const float*)d_in[16];
  float* out = (float*)d_out;

  char* ws = (char*)d_ws;
  size_t off = 0;
  auto alloc = [&](size_t bytes) {
    char* p = ws + off;
    off += (bytes + 255) & ~(size_t)255;
    return p;
  };
  float* deg  = (float*)alloc((size_t)B_ * N_ * 4);          // raw col sums
  bf16* Anbf  = (bf16*)alloc((size_t)B_ * N_ * N_ * 2);      // 64 MB
  bf16* W1t   = (bf16*)alloc((size_t)D_ * N_ * 2);           // [512 x 1024]
  bf16* W2t   = (bf16*)alloc((size_t)D_ * D_ * 2);           // [512 x 512]
  bf16* T12t  = (bf16*)alloc((size_t)B_ * D_ * N_ * 2);      // T1t then T2t
  bf16* H1    = (bf16*)alloc((size_t)B_ * N_ * D_ * 2);      // [b][1024][512]
  bf16* Abf   = (bf16*)alloc((size_t)B_ * N_ * N_ * 2);      // later reused as H2
  bf16* H2    = Abf;                                          // Abf dead after GEMM1
  float* zp   = (float*)alloc((size_t)B_ * D_ * 4);

  hipMemsetAsync(deg, 0, (size_t)B_ * N_ * 4, stream);
  hipMemsetAsync(zp, 0, (size_t)B_ * D_ * 4, stream);

  k_deg<<<dim3(8, B_), 256, 0, stream>>>(A, deg, Abf);
  k_build<<<dim3(16, 16, B_), 256, 0, stream>>>(Abf, deg, Anbf);
  k_transpose<<<192, 256, 0, stream>>>(W1, W1t, W2, W2t);

  // G1: T1t[512,1024] = W1t[512,1024] @ Abf[1024,1024]^T   (T1 = A @ W1, transposed)
  k_gemm<false, false><<<dim3(8, 4, B_), 256, 0, stream>>>(
      W1t, 0, Abf, (size_t)N_ * N_, T12t, (size_t)D_ * N_, nullptr, N_, N_);
  // G2: H1[1024,512] = relu(An[1024,1024] @ T1t[512,1024]^T + b1)
  k_gemm<true, true><<<dim3(4, 8, B_), 256, 0, stream>>>(
      Anbf, (size_t)N_ * N_, T12t, (size_t)D_ * N_, H1, (size_t)N_ * D_, b1, D_, N_);
  // G3: T2t[512,1024] = W2t[512,512] @ H1[1024,512]^T      (T2 = H1 @ W2, transposed)
  k_gemm<false, false><<<dim3(8, 4, B_), 256, 0, stream>>>(
      W2t, 0, H1, (size_t)N_ * D_, T12t, (size_t)D_ * N_, nullptr, N_, D_);
  // G4: H2[1024,512] = An[1024,1024] @ T2t[512,1024]^T + b2
  k_gemm<true, false><<<dim3(4, 8, B_), 256, 0, stream>>>(
      Anbf, (size_t)N_ * N_, T12t, (size_t)D_ * N_, H2, (size_t)N_ * D_, b2, D_, N_);

  k_lnpool<<<dim3(16, B_), 256, 0, stream>>>(H2, lng, lnb, zp);
  k_cls<<<B_, 128, 0, stream>>>(zp, Wc1, bc1, g1, t1, Wc2, bc2, g2, t2, Wc3, bc3, out);
}